// Round 4
// baseline (75.880 us; speedup 1.0000x reference)
//
#include <hip/hip_runtime.h>

#define NNODE 8
#define FDIM 512
#define HDIM 256
#define ODIM 128
#define BATCH 8192
#define NEDGE 56
#define FBLOCKS 16
#define FS (FDIM / FBLOCKS)     // 32
#define SPB 16
#define NBLK (BATCH / SPB)      // 512

// ws float offsets
#define OFF_PART 0                              // 16 * 9 * 256
#define OFF_TAU  (FBLOCKS * 9 * HDIM)           // 36864: tau_sorted[8][256]
#define OFF_AHAT (OFF_TAU + NNODE * HDIM)       // 38912: Ahat[64]
#define OFF_TABA (OFF_AHAT + 128)               // 39040: A table [8][257][128]
#define TABJ     (257 * ODIM)                   // 32896 floats per j
#define OFF_TABB (OFF_TABA + NNODE * TABJ)      // B table [8][257][128]

// ---------------- stage: partial Y = NF@W1 slices, partial s1 ----------------
__global__ __launch_bounds__(256) void gnn_stage(const float* __restrict__ nf,
                                                 const float* __restrict__ W1,
                                                 float* __restrict__ ws) {
    const int k = blockIdx.x;
    const int t = threadIdx.x;  // h index
    __shared__ float nf_s[NNODE][FS];

    {
        int n = t >> 5, f = t & 31;
        nf_s[n][f] = nf[n * FDIM + k * FS + f];
    }
    __syncthreads();

    float s1 = 0.f;
    float y[NNODE];
#pragma unroll
    for (int n = 0; n < NNODE; n++) y[n] = 0.f;

#pragma unroll
    for (int ff = 0; ff < FS; ff++) {
        float wf = W1[(k * FS + ff) * HDIM + t];
        s1 += wf;
#pragma unroll
        for (int n = 0; n < NNODE; n++) y[n] = fmaf(nf_s[n][ff], wf, y[n]);
    }

    float* p = ws + (size_t)k * 9 * HDIM;
#pragma unroll
    for (int n = 0; n < NNODE; n++) p[n * HDIM + t] = y[n];
    p[8 * HDIM + t] = s1;
}

// ------------- build: per node j, knot list + prefix tables A,B -------------
__global__ __launch_bounds__(256) void gnn_build(const float* __restrict__ ea,
                                                 const float* __restrict__ b1,
                                                 const float* __restrict__ W2,
                                                 float* __restrict__ ws) {
    const int j = blockIdx.x;     // node index
    const int t = threadIdx.x;    // h index in phases 1-3
    __shared__ float ea_s[NEDGE];
    __shared__ float A_s[64];
    __shared__ float P_s[HDIM];
    __shared__ float k_s[HDIM];
    __shared__ float tau_s[HDIM];
    __shared__ int   hs[HDIM];
    __shared__ float mj_sh;

    if (t < NEDGE) ea_s[t] = ea[t];

    // reduce stage partials (t = h)
    float y[NNODE];
    float s1 = 0.f;
#pragma unroll
    for (int n = 0; n < NNODE; n++) y[n] = 0.f;
#pragma unroll 4
    for (int k = 0; k < FBLOCKS; k++) {
        const float* p = ws + (size_t)k * 9 * HDIM;
#pragma unroll
        for (int n = 0; n < NNODE; n++) y[n] += p[n * HDIM + t];
        s1 += p[8 * HDIM + t];
    }
    __syncthreads();

    if (t == 0) {
        float A[NNODE][NNODE];
        for (int i = 0; i < NNODE; i++)
            for (int q = 0; q < NNODE; q++) A[i][q] = (i == q) ? 1.f : 0.f;
        for (int e = 0; e < NEDGE; e++) {
            int i = e / (NNODE - 1);
            int qq = e % (NNODE - 1);
            int q = qq + (qq >= i ? 1 : 0);
            A[q][i] += ea_s[e];          // A[DST][SRC]
        }
        float dinv[NNODE];
        for (int i = 0; i < NNODE; i++) {
            float d = 0.f;
            for (int q = 0; q < NNODE; q++) d += A[i][q];
            dinv[i] = d > 0.f ? 1.0f / sqrtf(d) : 0.f;
        }
        for (int i = 0; i < NNODE; i++)
            for (int q = 0; q < NNODE; q++) A_s[i * NNODE + q] = dinv[i] * A[i][q] * dinv[q];
        float mm = 0.f;
        for (int r = 0; r < NNODE; r++) mm += A_s[r * NNODE + j];
        mj_sh = mm * (1.0f / NNODE);
    }
    __syncthreads();

    // P[j][h], kappa[h], tau[h]
    float P = b1[t];
#pragma unroll
    for (int n = 0; n < NNODE; n++) P = fmaf(A_s[j * NNODE + n], y[n], P);
    float kap = 0.1f * s1;
    float tau = (kap != 0.f) ? (-P / kap) : __builtin_inff();
    P_s[t] = P;
    k_s[t] = kap;
    tau_s[t] = tau;
    __syncthreads();

    // rank-sort (unique ranks, deterministic tie-break by index)
    {
        int r = 0;
        for (int k = 0; k < HDIM; k++) {
            float tk = tau_s[k];
            r += (tk < tau) || (tk == tau && k < t);
        }
        hs[r] = t;
        ws[OFF_TAU + j * HDIM + r] = tau;
    }
    if (j == 0 && t < 64) ws[OFF_AHAT + t] = A_s[t];
    __syncthreads();

    // prefix tables (threads 0..127, o = t)
    if (t < ODIM) {
        const int o = t;
        const float mj = mj_sh;
        float a0 = 0.f, b0 = 0.f;
        // base state at c = -inf: kappa<0 active; kappa==0 && P>0 always active
#pragma unroll 4
        for (int h = 0; h < HDIM; h++) {
            float w2v = W2[h * ODIM + o];
            float kk = k_s[h], pp = P_s[h];
            if (kk < 0.f) {
                a0 = fmaf(pp, w2v, a0);
                b0 = fmaf(kk, w2v, b0);
            } else if (kk == 0.f && pp > 0.f) {
                a0 = fmaf(pp, w2v, a0);
            }
        }
        float* TA = ws + OFF_TABA + (size_t)j * TABJ;
        float* TB = ws + OFF_TABB + (size_t)j * TABJ;
        TA[o] = mj * a0;
        TB[o] = mj * b0;
        // walk events in knot order
#pragma unroll 2
        for (int r = 0; r < HDIM; r++) {
            int e = hs[r];
            float kk = k_s[e], pp = P_s[e];
            float sgn = (kk > 0.f) ? 1.f : ((kk < 0.f) ? -1.f : 0.f);
            float w2v = W2[e * ODIM + o];
            a0 = fmaf(sgn * pp, w2v, a0);
            b0 = fmaf(sgn * kk, w2v, b0);
            TA[(size_t)(r + 1) * ODIM + o] = mj * a0;
            TB[(size_t)(r + 1) * ODIM + o] = mj * b0;
        }
    }
}

// ----------------------------- main: per-sample -----------------------------
__global__ __launch_bounds__(256) void gnn_main(const float* __restrict__ latent,
                                                const float* __restrict__ b2,
                                                const float* __restrict__ ws,
                                                float* __restrict__ out) {
    const int t = threadIdx.x;
    const int bs = blockIdx.x * SPB;

    __shared__ float tau_s[NNODE][HDIM];   // 8 KiB
    __shared__ float A_s[64];
    __shared__ float lat_s[SPB][NNODE];
    __shared__ float cc_s[SPB][NNODE];
    __shared__ int   rr_s[SPB][NNODE];

    for (int k = t; k < NNODE * HDIM; k += 256)
        ((float*)tau_s)[k] = ws[OFF_TAU + k];
    if (t < 64) A_s[t] = ws[OFF_AHAT + t];
    if (t >= 128) {
        int u = t - 128;
        int s = u >> 3, q = u & 7;
        lat_s[s][q] = latent[(size_t)(bs + s) * FDIM + q];
    }
    __syncthreads();

    if (t < SPB * NNODE) {   // 128 threads: (s, i)
        int s = t >> 3, i = t & 7;
        float mx = -1e30f;
#pragma unroll
        for (int q = 0; q < NNODE; q++) mx = fmaxf(mx, lat_s[s][q]);
        float sum = 0.f, acc = 0.f;
#pragma unroll
        for (int q = 0; q < NNODE; q++) {
            float e = expf(lat_s[s][q] - mx);
            sum += e;
            acc = fmaf(A_s[i * NNODE + q], e, acc);
        }
        float c = acc / sum;
        cc_s[s][i] = c;
        // r = #{tau < c}  (lower_bound)
        int lo = 0, hi = HDIM;
        while (lo < hi) {
            int mid = (lo + hi) >> 1;
            if (tau_s[i][mid] < c) lo = mid + 1; else hi = mid;
        }
        rr_s[s][i] = lo;
    }
    __syncthreads();

    const int o = t & (ODIM - 1);
    const int sh = t >> 7;                 // 0 or 1
    const float* TA = ws + OFF_TABA;
    const float* TB = ws + OFF_TABB;
    const float bo = b2[o];

#pragma unroll 2
    for (int s = sh; s < SPB; s += 2) {
        float acc = bo;
#pragma unroll
        for (int j = 0; j < NNODE; j++) {
            int r = rr_s[s][j];
            float c = cc_s[s][j];
            size_t base = (size_t)j * TABJ + (size_t)r * ODIM + o;
            float av = TA[base];
            float bv = TB[base];
            acc += fmaf(c, bv, av);
        }
        out[(size_t)(bs + s) * ODIM + o] = acc;
    }
}

extern "C" void kernel_launch(void* const* d_in, const int* in_sizes, int n_in,
                              void* d_out, int out_size, void* d_ws, size_t ws_size,
                              hipStream_t stream) {
    const float* latent = (const float*)d_in[0];
    const float* nf     = (const float*)d_in[1];
    const float* ea     = (const float*)d_in[2];
    const float* W1     = (const float*)d_in[3];
    const float* b1     = (const float*)d_in[4];
    const float* W2     = (const float*)d_in[5];
    const float* b2     = (const float*)d_in[6];
    float* out = (float*)d_out;
    float* ws  = (float*)d_ws;

    hipLaunchKernelGGL(gnn_stage, dim3(FBLOCKS), dim3(256), 0, stream, nf, W1, ws);
    hipLaunchKernelGGL(gnn_build, dim3(NNODE), dim3(256), 0, stream, ea, b1, W2, ws);
    hipLaunchKernelGGL(gnn_main, dim3(NBLK), dim3(256), 0, stream, latent, b2, ws, out);
}

// Round 5
// 34.617 us; speedup vs baseline: 2.1920x; 2.1920x over previous
//
#include <hip/hip_runtime.h>

#define NNODE 8
#define FDIM 512
#define HDIM 256
#define ODIM 128
#define BATCH 8192
#define NEDGE 56
#define FBLOCKS 16
#define FS (FDIM / FBLOCKS)     // 32
#define SPB 16
#define NBLK (BATCH / SPB)      // 512

#define OCH 16                  // o-columns per tab block
#define QCH (ODIM / OCH)        // 8
#define NGR 16                  // r-groups (chunks) per tab block
#define CHK (HDIM / NGR)        // 16

// ws float offsets
#define OFF_PART 0                                // 16*9*256 = 36864
#define OFF_TAU  (FBLOCKS * 9 * HDIM)             // 36864
#define OFF_AHAT (OFF_TAU + NNODE * HDIM)         // 38912
#define OFF_EI   (OFF_AHAT + 128)                 // 39040 (ints)
#define OFF_PE   (OFF_EI + NNODE * HDIM)          // 41088
#define OFF_KE   (OFF_PE + NNODE * HDIM)          // 43136
#define OFF_BP   (OFF_KE + NNODE * HDIM)          // 45184
#define OFF_BK   (OFF_BP + NNODE * HDIM)          // 47232
#define OFF_TAB  (OFF_BK + NNODE * HDIM)          // 49280 (even, float2-aligned)

// ---------------- stage: partial Y = NF@W1 slices, partial s1 ----------------
__global__ __launch_bounds__(256) void gnn_stage(const float* __restrict__ nf,
                                                 const float* __restrict__ W1,
                                                 float* __restrict__ ws) {
    const int k = blockIdx.x;
    const int t = threadIdx.x;  // h index
    __shared__ float nf_s[NNODE][FS];

    {
        int n = t >> 5, f = t & 31;
        nf_s[n][f] = nf[n * FDIM + k * FS + f];
    }
    __syncthreads();

    float s1 = 0.f;
    float y[NNODE];
#pragma unroll
    for (int n = 0; n < NNODE; n++) y[n] = 0.f;

#pragma unroll
    for (int ff = 0; ff < FS; ff++) {
        float wf = W1[(k * FS + ff) * HDIM + t];
        s1 += wf;
#pragma unroll
        for (int n = 0; n < NNODE; n++) y[n] = fmaf(nf_s[n][ff], wf, y[n]);
    }

    float* p = ws + (size_t)k * 9 * HDIM;
#pragma unroll
    for (int n = 0; n < NNODE; n++) p[n * HDIM + t] = y[n];
    p[8 * HDIM + t] = s1;
}

// ---- prep: per node j: P, kappa, tau, rank-sort, event-ordered coeffs ----
__global__ __launch_bounds__(256) void gnn_prep(const float* __restrict__ ea,
                                                const float* __restrict__ b1,
                                                float* __restrict__ ws) {
    const int j = blockIdx.x;
    const int t = threadIdx.x;   // h index
    __shared__ float ea_s[NEDGE];
    __shared__ float A_s[64];
    __shared__ float P_s[HDIM];
    __shared__ float k_s[HDIM];
    __shared__ float tau_s[HDIM];
    __shared__ int   hs[HDIM];
    __shared__ float mj_sh;

    if (t < NEDGE) ea_s[t] = ea[t];

    // reduce stage partials (t = h)
    float y[NNODE];
    float s1 = 0.f;
#pragma unroll
    for (int n = 0; n < NNODE; n++) y[n] = 0.f;
#pragma unroll 4
    for (int k = 0; k < FBLOCKS; k++) {
        const float* p = ws + (size_t)k * 9 * HDIM;
#pragma unroll
        for (int n = 0; n < NNODE; n++) y[n] += p[n * HDIM + t];
        s1 += p[8 * HDIM + t];
    }
    __syncthreads();

    if (t == 0) {
        float A[NNODE][NNODE];
        for (int i = 0; i < NNODE; i++)
            for (int q = 0; q < NNODE; q++) A[i][q] = (i == q) ? 1.f : 0.f;
        for (int e = 0; e < NEDGE; e++) {
            int i = e / (NNODE - 1);
            int qq = e % (NNODE - 1);
            int q = qq + (qq >= i ? 1 : 0);
            A[q][i] += ea_s[e];          // A[DST][SRC]
        }
        float dinv[NNODE];
        for (int i = 0; i < NNODE; i++) {
            float d = 0.f;
            for (int q = 0; q < NNODE; q++) d += A[i][q];
            dinv[i] = d > 0.f ? 1.0f / sqrtf(d) : 0.f;
        }
        for (int i = 0; i < NNODE; i++)
            for (int q = 0; q < NNODE; q++) A_s[i * NNODE + q] = dinv[i] * A[i][q] * dinv[q];
        float mm = 0.f;
        for (int r = 0; r < NNODE; r++) mm += A_s[r * NNODE + j];
        mj_sh = mm * (1.0f / NNODE);
    }
    __syncthreads();

    const float mj = mj_sh;
    float P = b1[t];
#pragma unroll
    for (int n = 0; n < NNODE; n++) P = fmaf(A_s[j * NNODE + n], y[n], P);
    float kap = 0.1f * s1;
    float tau = (kap != 0.f) ? (-P / kap) : __builtin_inff();
    P_s[t] = P;
    k_s[t] = kap;
    tau_s[t] = tau;

    // base-state coefficients (c = -inf active set), mj folded
    {
        float bp = (kap < 0.f || (kap == 0.f && P > 0.f)) ? P : 0.f;
        float bk = (kap < 0.f) ? kap : 0.f;
        ws[OFF_BP + j * HDIM + t] = mj * bp;
        ws[OFF_BK + j * HDIM + t] = mj * bk;
    }
    __syncthreads();

    // rank-sort (unique ranks, tie-break by index)
    {
        int r = 0;
        for (int k = 0; k < HDIM; k++) {
            float tk = tau_s[k];
            r += (tk < tau) || (tk == tau && k < t);
        }
        hs[r] = t;
    }
    __syncthreads();

    // thread t acts as rank r: event-ordered arrays
    {
        int h2 = hs[t];
        float kk = k_s[h2], pp = P_s[h2];
        float sgn = (kk > 0.f) ? 1.f : ((kk < 0.f) ? -1.f : 0.f);
        ((int*)ws)[OFF_EI + j * HDIM + t] = h2;
        ws[OFF_PE + j * HDIM + t] = mj * sgn * pp;
        ws[OFF_KE + j * HDIM + t] = mj * sgn * kk;
        ws[OFF_TAU + j * HDIM + t] = tau_s[h2];
    }
    if (j == 0 && t < 64) ws[OFF_AHAT + t] = A_s[t];
}

// ---- tab: parallel prefix tables, float2(A,B) interleaved, b2 folded in ----
__global__ __launch_bounds__(256) void gnn_tab(const float* __restrict__ W2,
                                               const float* __restrict__ b2,
                                               float* __restrict__ ws) {
    const int blk = blockIdx.x;          // 0..63
    const int j = blk >> 3;
    const int q = blk & (QCH - 1);
    const int obase = q * OCH;
    const int t = threadIdx.x;
    const int oc = t & (OCH - 1);
    const int rr = t >> 4;               // 0..15

    __shared__ int   ei_s[HDIM];
    __shared__ float pe_s[HDIM], ke_s[HDIM], bp_s[HDIM], bk_s[HDIM];
    __shared__ float cta[NGR][OCH], ctb[NGR][OCH];   // base partials
    __shared__ float eta[NGR][OCH], etb[NGR][OCH];   // event chunk totals -> offsets

    if (t < HDIM) {
        ei_s[t] = ((const int*)ws)[OFF_EI + j * HDIM + t];
        pe_s[t] = ws[OFF_PE + j * HDIM + t];
        ke_s[t] = ws[OFF_KE + j * HDIM + t];
        bp_s[t] = ws[OFF_BP + j * HDIM + t];
        bk_s[t] = ws[OFF_BK + j * HDIM + t];
    }
    __syncthreads();

    // base partial reduction over h (natural order)
    {
        float ba = 0.f, bb = 0.f;
#pragma unroll
        for (int k = 0; k < CHK; k++) {
            int h = rr * CHK + k;
            float w2v = W2[h * ODIM + obase + oc];
            ba = fmaf(bp_s[h], w2v, ba);
            bb = fmaf(bk_s[h], w2v, bb);
        }
        cta[rr][oc] = ba;
        ctb[rr][oc] = bb;
    }
    // event chunk totals (sorted order)
    {
        float sa = 0.f, sb = 0.f;
#pragma unroll
        for (int k = 0; k < CHK; k++) {
            int r = rr * CHK + k;
            float w2v = W2[ei_s[r] * ODIM + obase + oc];
            sa = fmaf(pe_s[r], w2v, sa);
            sb = fmaf(ke_s[r], w2v, sb);
        }
        eta[rr][oc] = sa;
        etb[rr][oc] = sb;
    }
    __syncthreads();

    float2* TAB = (float2*)(ws + OFF_TAB);

    // column owners: base total, write row 0, exclusive-scan event chunks
    if (rr == 0) {
        float accA = 0.f, accB = 0.f;
#pragma unroll
        for (int g = 0; g < NGR; g++) { accA += cta[g][oc]; accB += ctb[g][oc]; }
        if (j == 0) accA += b2[obase + oc];
        TAB[(size_t)(j * 257) * ODIM + obase + oc] = make_float2(accA, accB);
#pragma unroll
        for (int g = 0; g < NGR; g++) {
            float ta = eta[g][oc], tb = etb[g][oc];
            eta[g][oc] = accA; etb[g][oc] = accB;
            accA += ta; accB += tb;
        }
    }
    __syncthreads();

    // pass 2: recompute (L2-hot) with running offset, write rows r+1
    {
        float ra = eta[rr][oc], rb = etb[rr][oc];
#pragma unroll
        for (int k = 0; k < CHK; k++) {
            int r = rr * CHK + k;
            float w2v = W2[ei_s[r] * ODIM + obase + oc];
            ra = fmaf(pe_s[r], w2v, ra);
            rb = fmaf(ke_s[r], w2v, rb);
            TAB[(size_t)(j * 257 + r + 1) * ODIM + obase + oc] = make_float2(ra, rb);
        }
    }
}

// ----------------------------- main: per-sample -----------------------------
__global__ __launch_bounds__(256) void gnn_main(const float* __restrict__ latent,
                                                const float* __restrict__ ws,
                                                float* __restrict__ out) {
    const int t = threadIdx.x;
    const int bs = blockIdx.x * SPB;

    __shared__ float tau_s[NNODE][HDIM];   // 8 KiB
    __shared__ float A_s[64];
    __shared__ float lat_s[SPB][NNODE];
    __shared__ float cc_s[SPB][NNODE];
    __shared__ int   rr_s[SPB][NNODE];

    for (int k = t; k < NNODE * HDIM; k += 256)
        ((float*)tau_s)[k] = ws[OFF_TAU + k];
    if (t < 64) A_s[t] = ws[OFF_AHAT + t];
    if (t >= 128) {
        int u = t - 128;
        int s = u >> 3, qq = u & 7;
        lat_s[s][qq] = latent[(size_t)(bs + s) * FDIM + qq];
    }
    __syncthreads();

    if (t < SPB * NNODE) {   // 128 threads: (s, i)
        int s = t >> 3, i = t & 7;
        float mx = -1e30f;
#pragma unroll
        for (int q = 0; q < NNODE; q++) mx = fmaxf(mx, lat_s[s][q]);
        float sum = 0.f, acc = 0.f;
#pragma unroll
        for (int q = 0; q < NNODE; q++) {
            float e = expf(lat_s[s][q] - mx);
            sum += e;
            acc = fmaf(A_s[i * NNODE + q], e, acc);
        }
        float c = acc / sum;
        cc_s[s][i] = c;
        int lo = 0, hi = HDIM;
        while (lo < hi) {
            int mid = (lo + hi) >> 1;
            if (tau_s[i][mid] < c) lo = mid + 1; else hi = mid;
        }
        rr_s[s][i] = lo;
    }
    __syncthreads();

    const int o = t & (ODIM - 1);
    const int sh = t >> 7;                 // 0 or 1
    const float2* TAB = (const float2*)(ws + OFF_TAB);

#pragma unroll 2
    for (int s = sh; s < SPB; s += 2) {
        float acc = 0.f;
#pragma unroll
        for (int j = 0; j < NNODE; j++) {
            int r = rr_s[s][j];
            float c = cc_s[s][j];
            float2 ab = TAB[(size_t)(j * 257 + r) * ODIM + o];
            acc += fmaf(c, ab.y, ab.x);
        }
        out[(size_t)(bs + s) * ODIM + o] = acc;
    }
}

extern "C" void kernel_launch(void* const* d_in, const int* in_sizes, int n_in,
                              void* d_out, int out_size, void* d_ws, size_t ws_size,
                              hipStream_t stream) {
    const float* latent = (const float*)d_in[0];
    const float* nf     = (const float*)d_in[1];
    const float* ea     = (const float*)d_in[2];
    const float* W1     = (const float*)d_in[3];
    const float* b1     = (const float*)d_in[4];
    const float* W2     = (const float*)d_in[5];
    const float* b2     = (const float*)d_in[6];
    float* out = (float*)d_out;
    float* ws  = (float*)d_ws;

    hipLaunchKernelGGL(gnn_stage, dim3(FBLOCKS), dim3(256), 0, stream, nf, W1, ws);
    hipLaunchKernelGGL(gnn_prep, dim3(NNODE), dim3(256), 0, stream, ea, b1, ws);
    hipLaunchKernelGGL(gnn_tab, dim3(NNODE * QCH), dim3(256), 0, stream, W2, b2, ws);
    hipLaunchKernelGGL(gnn_main, dim3(NBLK), dim3(256), 0, stream, latent, ws, out);
}